// Round 1
// baseline (234.894 us; speedup 1.0000x reference)
//
#include <hip/hip_runtime.h>

// Multi-threshold spiking neuron scan.
// x: [T*B, C, H, W] fp32, T=4 fixed, K=8 thresholds thre[k]=thresh/2^k.
// Per spatial column (b,c,h,w): mem += x[t]; spike = largest thre[k] with
// mem >= 0.75*thre[k] (0 if none); out[t]=spike; mem -= spike.
// Memory-bound: 268 MB traffic -> ~43 us floor at 6.3 TB/s.

constexpr int T_STEPS = 4;
constexpr int K_THRESH = 8;

__global__ __launch_bounds__(256) void snn_mth_kernel(
    const float* __restrict__ x,
    const float* __restrict__ p_thresh,
    float* __restrict__ out,
    int s4)  // spatial elements per timestep / 4
{
    int i = blockIdx.x * blockDim.x + threadIdx.x;
    if (i >= s4) return;

    const float thresh = *p_thresh;

    // thre[k] = thresh * 2^-k (exact), thr75[k] = 0.75*thresh * 2^-k.
    // (thresh*0.75 rounds once, then exact halvings — identical to the
    // reference's (thresh/2^k)*0.75 per-k results.)
    float thre[K_THRESH], thr75[K_THRESH];
    {
        float tk = thresh;
        float t75 = 0.75f * thresh;
#pragma unroll
        for (int k = 0; k < K_THRESH; ++k) {
            thre[k] = tk;
            thr75[k] = t75;
            tk *= 0.5f;
            t75 *= 0.5f;
        }
    }

    const float4* __restrict__ xv = reinterpret_cast<const float4*>(x);
    float4* __restrict__ ov = reinterpret_cast<float4*>(out);

    float4 mem = make_float4(0.f, 0.f, 0.f, 0.f);

#pragma unroll
    for (int t = 0; t < T_STEPS; ++t) {
        float4 xc = xv[(size_t)t * s4 + i];
        mem.x += xc.x;
        mem.y += xc.y;
        mem.z += xc.z;
        mem.w += xc.w;

        float4 sp = make_float4(0.f, 0.f, 0.f, 0.f);
        // Iterate k from smallest threshold up: larger thresholds override,
        // leaving the largest crossed threshold. Branch-free cmp+cndmask.
#pragma unroll
        for (int k = K_THRESH - 1; k >= 0; --k) {
            sp.x = (mem.x >= thr75[k]) ? thre[k] : sp.x;
            sp.y = (mem.y >= thr75[k]) ? thre[k] : sp.y;
            sp.z = (mem.z >= thr75[k]) ? thre[k] : sp.z;
            sp.w = (mem.w >= thr75[k]) ? thre[k] : sp.w;
        }

        ov[(size_t)t * s4 + i] = sp;

        mem.x -= sp.x;
        mem.y -= sp.y;
        mem.z -= sp.z;
        mem.w -= sp.w;
    }
}

extern "C" void kernel_launch(void* const* d_in, const int* in_sizes, int n_in,
                              void* d_out, int out_size, void* d_ws, size_t ws_size,
                              hipStream_t stream) {
    const float* x = (const float*)d_in[0];
    const float* p_thresh = (const float*)d_in[1];
    float* out = (float*)d_out;

    const int total = in_sizes[0];          // T*B*C*H*W
    const int S = total / T_STEPS;          // spatial elements per timestep
    const int s4 = S >> 2;                  // float4 columns (S divisible by 4)

    const int block = 256;
    const int grid = (s4 + block - 1) / block;
    snn_mth_kernel<<<grid, block, 0, stream>>>(x, p_thresh, out, s4);
}